// Round 3
// baseline (216.544 us; speedup 1.0000x reference)
//
#include <hip/hip_runtime.h>

// VectorQuantizer, split-bf16 MFMA, spill-free sweep (round 3).
// scores = -2*E@C^T + ||c||^2; argmin_k; gather; mse losses.
//   -2e = ehi+elo (bf16 RNE), c = chi+clo; -2dot ~= (ehi+elo)@chi + ehi@clo
// MFMA 32x32x16, D[m=codeword][n=enc_row]. Per wave: one codeword-tile PAIR
// vs all 4 enc-row tiles (acc 2x4x16 = 128 regs), A-frags streamed from L2
// per k-chunk (transient), B-frags from LDS. Rows with top-2 gap < MARGIN
// get exact fp32 rescan.
// Output: [0,N) idx as float | [N,N+N*D) quantized | +0,1,2 = vq,embed,commit.

#define NROWS 65536
#define KCB   1024
#define DIM   128
#define DV    32
#define MSE_DENOM 8388608.0f
#define MARGIN 3.0e-5f
#define FLAGCAP 16384

#define WS_CNORM_F 256      // float index: cnorm[1024]
#define WS_LIST_B  8192     // 16384 ints
#define WS_PH_B    73728    // 256 KB packed codebook hi frags
#define WS_PL_B    335872   // 256 KB packed codebook lo frags
#define WS_NEEDED  598016

typedef __attribute__((ext_vector_type(8)))  short short8;
typedef __attribute__((ext_vector_type(16))) float float16v;
typedef __attribute__((ext_vector_type(4)))  float floatx4;
union U4S8 { uint4 u; short8 s; };
union F4A  { floatx4 v; float f[4]; };

__device__ __forceinline__ unsigned bf16rne(float x) {
  unsigned u = __float_as_uint(x);
  return (u + 0x7FFFu + ((u >> 16) & 1u)) >> 16;
}
__device__ __forceinline__ void split2(float y, unsigned& hb, unsigned& lb) {
  hb = bf16rne(y);
  float hf = __uint_as_float(hb << 16);
  lb = bf16rne(y - hf);
}
__device__ __forceinline__ unsigned umn(unsigned a, unsigned b) { return a < b ? a : b; }
__device__ __forceinline__ unsigned umx(unsigned a, unsigned b) { return a > b ? a : b; }
__device__ __forceinline__ float unmap_score(unsigned up) {
  return (up & 0x80000000u) ? __uint_as_float(up ^ 0x80000000u) : __uint_as_float(~up);
}

// ---------- prep+pack fused: blocks 0..63 pack frags, 64..67 cnorm ----------
__global__ __launch_bounds__(256) void vq_prep_pack(const float* __restrict__ C,
                                                    float* __restrict__ wsf,
                                                    uint4* __restrict__ PH,
                                                    uint4* __restrict__ PL) {
  const int b = blockIdx.x, tid = threadIdx.x;
  if (b < 64) {
    int g = b * 256 + tid;
    int mt = g >> 9, s = (g >> 6) & 7, l = g & 63;
    int cw = mt * 32 + (l & 31);
    int k0 = s * 16 + (l >> 5) * 8;
    const float* src = C + (size_t)cw * DIM + k0;
    floatx4 x0 = *(const floatx4*)src;
    floatx4 x1 = *(const floatx4*)(src + 4);
    unsigned h[8], lo[8];
    split2(x0.x, h[0], lo[0]); split2(x0.y, h[1], lo[1]);
    split2(x0.z, h[2], lo[2]); split2(x0.w, h[3], lo[3]);
    split2(x1.x, h[4], lo[4]); split2(x1.y, h[5], lo[5]);
    split2(x1.z, h[6], lo[6]); split2(x1.w, h[7], lo[7]);
    PH[g] = make_uint4(h[0] | (h[1] << 16), h[2] | (h[3] << 16),
                       h[4] | (h[5] << 16), h[6] | (h[7] << 16));
    PL[g] = make_uint4(lo[0] | (lo[1] << 16), lo[2] | (lo[3] << 16),
                       lo[4] | (lo[5] << 16), lo[6] | (lo[7] << 16));
  } else {
    int k = (b - 64) * 256 + tid;
    if (k == 0) { wsf[0] = 0.0f; ((unsigned*)wsf)[1] = 0u; }
    const floatx4* c4 = (const floatx4*)C + (size_t)k * DV;
    float s = 0.f;
#pragma unroll 8
    for (int i = 0; i < DV; ++i) {
      floatx4 v = c4[i];
      s = fmaf(v.x, v.x, s); s = fmaf(v.y, v.y, s);
      s = fmaf(v.z, v.z, s); s = fmaf(v.w, v.w, s);
    }
    wsf[WS_CNORM_F + k] = s;
  }
}

// ---------- main: MFMA sweep + argmin + loss + gather ----------
__global__ __launch_bounds__(256, 2) void vq_main3(const float* __restrict__ E,
                                                   const float* __restrict__ C,
                                                   float* __restrict__ wsf,
                                                   float* __restrict__ out) {
  __shared__ uint4 EH[2048];          // 128 rows x 16 col-chunks, frag-linear
  __shared__ uint4 EL[2048];
  __shared__ float CN[1024];
  __shared__ float PART[256];         // [row][half] partial ||e||^2
  __shared__ uint2 M2[512];           // [wave][row] packed best/second
  __shared__ int   BI[128];

  const int tid  = threadIdx.x;
  const int w    = tid >> 6;
  const int l    = tid & 63;
  const int half = l >> 5;
  const int rr   = l & 31;
  const int row0 = blockIdx.x * 128;

  const uint4* PH = (const uint4*)((const char*)wsf + WS_PH_B);
  const uint4* PL = (const uint4*)((const char*)wsf + WS_PL_B);

  // ---- stage E tile (nontemporal reads; split hi/lo once per block) ----
  {
    int r = w * 32 + rr;
    const float* eb = E + (size_t)(row0 + r) * DIM + half * 64;
    float s2 = 0.f;
#pragma unroll
    for (int i = 0; i < 8; ++i) {
      floatx4 x0 = __builtin_nontemporal_load((const floatx4*)(eb + i * 8));
      floatx4 x1 = __builtin_nontemporal_load((const floatx4*)(eb + i * 8 + 4));
      s2 = fmaf(x0.x, x0.x, s2); s2 = fmaf(x0.y, x0.y, s2);
      s2 = fmaf(x0.z, x0.z, s2); s2 = fmaf(x0.w, x0.w, s2);
      s2 = fmaf(x1.x, x1.x, s2); s2 = fmaf(x1.y, x1.y, s2);
      s2 = fmaf(x1.z, x1.z, s2); s2 = fmaf(x1.w, x1.w, s2);
      unsigned h[8], lo[8];
      split2(-2.f * x0.x, h[0], lo[0]); split2(-2.f * x0.y, h[1], lo[1]);
      split2(-2.f * x0.z, h[2], lo[2]); split2(-2.f * x0.w, h[3], lo[3]);
      split2(-2.f * x1.x, h[4], lo[4]); split2(-2.f * x1.y, h[5], lo[5]);
      split2(-2.f * x1.z, h[6], lo[6]); split2(-2.f * x1.w, h[7], lo[7]);
      int a16 = w * 512 + (half * 8 + i) * 32 + rr;
      EH[a16] = make_uint4(h[0] | (h[1] << 16), h[2] | (h[3] << 16),
                           h[4] | (h[5] << 16), h[6] | (h[7] << 16));
      EL[a16] = make_uint4(lo[0] | (lo[1] << 16), lo[2] | (lo[3] << 16),
                           lo[4] | (lo[5] << 16), lo[6] | (lo[7] << 16));
    }
    PART[r * 2 + half] = s2;
    ((floatx4*)CN)[tid] = ((const floatx4*)(wsf + WS_CNORM_F))[tid];
  }
  __syncthreads();

  unsigned best[4], second[4];
#pragma unroll
  for (int n = 0; n < 4; ++n) { best[n] = 0xFFFFFFFFu; second[n] = 0xFFFFFFFFu; }

  // ---- sweep: wave w covers mtiles 8w..8w+7 as 4 pairs; all 4 ntiles ----
  for (int g = 0; g < 4; ++g) {
    const int m0 = (w * 4 + g) * 2;
    float16v acc[2][4];
#pragma unroll
    for (int t = 0; t < 2; ++t)
#pragma unroll
      for (int n = 0; n < 4; ++n)
#pragma unroll
        for (int r2 = 0; r2 < 16; ++r2) acc[t][n][r2] = 0.f;

#pragma unroll
    for (int s = 0; s < 8; ++s) {
      U4S8 a0h, a0l, a1h, a1l;
      a0h.u = PH[(size_t)((m0 + 0) * 8 + s) * 64 + l];
      a0l.u = PL[(size_t)((m0 + 0) * 8 + s) * 64 + l];
      a1h.u = PH[(size_t)((m0 + 1) * 8 + s) * 64 + l];
      a1l.u = PL[(size_t)((m0 + 1) * 8 + s) * 64 + l];
#pragma unroll
      for (int n = 0; n < 4; ++n) {
        U4S8 bh, bl;
        bh.u = EH[n * 512 + (s * 2 + half) * 32 + rr];
        bl.u = EL[n * 512 + (s * 2 + half) * 32 + rr];
        acc[0][n] = __builtin_amdgcn_mfma_f32_32x32x16_bf16(a0h.s, bh.s, acc[0][n], 0, 0, 0);
        acc[1][n] = __builtin_amdgcn_mfma_f32_32x32x16_bf16(a1h.s, bh.s, acc[1][n], 0, 0, 0);
        acc[0][n] = __builtin_amdgcn_mfma_f32_32x32x16_bf16(a0l.s, bh.s, acc[0][n], 0, 0, 0);
        acc[1][n] = __builtin_amdgcn_mfma_f32_32x32x16_bf16(a1l.s, bh.s, acc[1][n], 0, 0, 0);
        acc[0][n] = __builtin_amdgcn_mfma_f32_32x32x16_bf16(a0h.s, bl.s, acc[0][n], 0, 0, 0);
        acc[1][n] = __builtin_amdgcn_mfma_f32_32x32x16_bf16(a1h.s, bl.s, acc[1][n], 0, 0, 0);
      }
    }

    // fold argmin (score = acc + cnorm; pack score|index, track best+second)
#pragma unroll
    for (int t = 0; t < 2; ++t) {
      const int mt = m0 + t;
      const unsigned cwb = (unsigned)(mt * 32 + half * 4);
      float cnv[16];
#pragma unroll
      for (int q = 0; q < 4; ++q) {
        F4A a; a.v = *(const floatx4*)&CN[mt * 32 + q * 8 + half * 4];
#pragma unroll
        for (int i2 = 0; i2 < 4; ++i2) cnv[q * 4 + i2] = a.f[i2];
      }
#pragma unroll
      for (int n = 0; n < 4; ++n)
#pragma unroll
        for (int reg = 0; reg < 16; ++reg) {
          const int q = reg >> 2, i2 = reg & 3;
          float sc = acc[t][n][reg] + cnv[reg];
          unsigned u = __float_as_uint(sc);
          u ^= ((unsigned)(((int)u) >> 31)) | 0x80000000u;
          u = (u & 0xFFFFFC00u) | (cwb + (unsigned)(q * 8 + i2));
          unsigned nb = umn(best[n], u);
          second[n] = umn(second[n], umx(best[n], u));
          best[n] = nb;
        }
    }
  }

  // ---- merge halves, stash per-wave results ----
#pragma unroll
  for (int n = 0; n < 4; ++n) {
    unsigned b = best[n], s = second[n];
    unsigned ob = (unsigned)__shfl_xor((int)b, 32, 64);
    unsigned os = (unsigned)__shfl_xor((int)s, 32, 64);
    unsigned nb = umn(b, ob);
    unsigned ns = umn(umn(s, os), umx(b, ob));
    if (half == 0) M2[w * 128 + n * 32 + rr] = make_uint2(nb, ns);
  }
  __syncthreads();

  // ---- final per-row: merge 4 waves, flag, loss, index ----
  if (tid < 128) {
    const int r = tid;
    uint2 p0 = M2[r];
    unsigned b = p0.x, s = p0.y;
#pragma unroll
    for (int ww = 1; ww < 4; ++ww) {
      uint2 p = M2[ww * 128 + r];
      s = umn(umn(s, p.y), umx(b, p.x));
      b = umn(b, p.x);
    }
    int   bi = (int)(b & 1023u);
    float bv = unmap_score(b & 0xFFFFFC00u);
    float sv = unmap_score(s & 0xFFFFFC00u);
    out[row0 + r] = (float)bi;
    BI[r] = bi;
    if (sv - bv < MARGIN) {
      unsigned idx = atomicAdd((unsigned*)wsf + 1, 1u);
      if (idx < FLAGCAP) ((int*)((char*)wsf + WS_LIST_B))[idx] = row0 + r;
    }
    float term = PART[r * 2] + PART[r * 2 + 1] + bv;
#pragma unroll
    for (int off = 32; off > 0; off >>= 1) term += __shfl_down(term, off);
    if ((tid & 63) == 0) atomicAdd(wsf, term);
  }
  __syncthreads();

  // ---- gather quantized_st (C rows L2-hot; nontemporal stores) ----
  const floatx4* C4   = (const floatx4*)C;
  floatx4*       out4 = (floatx4*)out;
#pragma unroll
  for (int it = 0; it < 16; ++it) {
    int flat = it * 256 + tid;
    int r = flat >> 5, d4 = flat & 31;
    floatx4 v = C4[(size_t)BI[r] * DV + d4];
    __builtin_nontemporal_store(v, &out4[(NROWS / 4) + (size_t)(row0 + r) * DV + d4]);
  }
}

// ---------- exact fp32 rescan of flagged rows + scalar losses ----------
__global__ __launch_bounds__(256) void vq_fix(const float* __restrict__ E,
                                              const float* __restrict__ C,
                                              float* __restrict__ wsf,
                                              float* __restrict__ out) {
  __shared__ floatx4 eL0[32], eL1[32];
  __shared__ float  sv0[256], sv1[256];
  __shared__ int    si0[256], si1[256];
  __shared__ int    RESi[2];
  const int tid = threadIdx.x;
  if (blockIdx.x == 0 && tid == 0) {
    float mse = wsf[0] / MSE_DENOM;
    out[NROWS + NROWS * DIM + 0] = 1.25f * mse;
    out[NROWS + NROWS * DIM + 1] = mse;
    out[NROWS + NROWS * DIM + 2] = mse;
  }
  const int* list = (const int*)((const char*)wsf + WS_LIST_B);
  int nf = (int)((const unsigned*)wsf)[1];
  if (nf > FLAGCAP) nf = FLAGCAP;
  const floatx4* E4 = (const floatx4*)E;
  const floatx4* C4 = (const floatx4*)C;
  const float*  cn = wsf + WS_CNORM_F;
  floatx4* out4 = (floatx4*)out;

  for (int pair = blockIdx.x; pair * 2 < nf; pair += gridDim.x) {
    const int r0 = list[pair * 2];
    const int r1 = (pair * 2 + 1 < nf) ? list[pair * 2 + 1] : r0;
    if (tid < 32) eL0[tid] = E4[(size_t)r0 * DV + tid];
    else if (tid < 64) eL1[tid - 32] = E4[(size_t)r1 * DV + (tid - 32)];
    __syncthreads();
    float bv0 = 3.0e38f, bv1 = 3.0e38f; int bi0 = 0, bi1 = 0;
#pragma unroll
    for (int j = 0; j < 4; ++j) {
      int k = j * 256 + tid;
      float d0 = 0.f, d1 = 0.f;
#pragma unroll 8
      for (int d4 = 0; d4 < 32; ++d4) {
        floatx4 c = C4[(size_t)k * DV + d4];
        floatx4 e0 = eL0[d4], e1 = eL1[d4];
        d0 = fmaf(c.x, e0.x, d0); d0 = fmaf(c.y, e0.y, d0);
        d0 = fmaf(c.z, e0.z, d0); d0 = fmaf(c.w, e0.w, d0);
        d1 = fmaf(c.x, e1.x, d1); d1 = fmaf(c.y, e1.y, d1);
        d1 = fmaf(c.z, e1.z, d1); d1 = fmaf(c.w, e1.w, d1);
      }
      float s0 = fmaf(-2.f, d0, cn[k]);
      float s1 = fmaf(-2.f, d1, cn[k]);
      if (s0 < bv0 || (s0 == bv0 && k < bi0)) { bv0 = s0; bi0 = k; }
      if (s1 < bv1 || (s1 == bv1 && k < bi1)) { bv1 = s1; bi1 = k; }
    }
    sv0[tid] = bv0; si0[tid] = bi0; sv1[tid] = bv1; si1[tid] = bi1;
    __syncthreads();
    if (tid < 64) {
      float v0 = sv0[tid]; int i0 = si0[tid];
      float v1 = sv1[tid]; int i1 = si1[tid];
#pragma unroll
      for (int q = 1; q < 4; ++q) {
        float w0 = sv0[tid + q * 64]; int j0 = si0[tid + q * 64];
        float w1 = sv1[tid + q * 64]; int j1 = si1[tid + q * 64];
        if (w0 < v0 || (w0 == v0 && j0 < i0)) { v0 = w0; i0 = j0; }
        if (w1 < v1 || (w1 == v1 && j1 < i1)) { v1 = w1; i1 = j1; }
      }
#pragma unroll
      for (int off = 32; off > 0; off >>= 1) {
        float w0 = __shfl_down(v0, off); int j0 = __shfl_down(i0, off);
        float w1 = __shfl_down(v1, off); int j1 = __shfl_down(i1, off);
        if (w0 < v0 || (w0 == v0 && j0 < i0)) { v0 = w0; i0 = j0; }
        if (w1 < v1 || (w1 == v1 && j1 < i1)) { v1 = w1; i1 = j1; }
      }
      if (tid == 0) {
        RESi[0] = i0; RESi[1] = i1;
        out[r0] = (float)i0; out[r1] = (float)i1;
      }
    }
    __syncthreads();
    if (tid < 32) out4[(NROWS / 4) + (size_t)r0 * DV + tid] = C4[(size_t)RESi[0] * DV + tid];
    else if (tid < 64) out4[(NROWS / 4) + (size_t)r1 * DV + (tid - 32)] = C4[(size_t)RESi[1] * DV + (tid - 32)];
    __syncthreads();
  }
}

extern "C" void kernel_launch(void* const* d_in, const int* in_sizes, int n_in,
                              void* d_out, int out_size, void* d_ws, size_t ws_size,
                              hipStream_t stream) {
  const float* E = (const float*)d_in[0];
  const float* C = (const float*)d_in[1];
  float* out = (float*)d_out;
  float* wsf = (float*)d_ws;
  uint4* PH = (uint4*)((char*)d_ws + WS_PH_B);
  uint4* PL = (uint4*)((char*)d_ws + WS_PL_B);

  vq_prep_pack<<<68, 256, 0, stream>>>(C, wsf, PH, PL);
  vq_main3<<<NROWS / 128, 256, 0, stream>>>(E, C, wsf, out);
  vq_fix<<<256, 256, 0, stream>>>(E, C, wsf, out);
}